// Round 4
// baseline (205.000 us; speedup 1.0000x reference)
//
#include <hip/hip_runtime.h>

// Problem constants (N,C,H,W) = (8,19,384,384)
#define NCLS 19
#define HW   147456            // 384*384
#define MPIX 1179648           // 8*384*384
#define NB   512               // histogram buckets per class (LDS-resident)
#define TPB  512               // hist block threads (8 waves)
#define NBLK 1024              // hist blocks: 4 blocks/CU -> 32 waves/CU (max)
#define HSZ  (NCLS * NB)       // 9728 packed u32 words per block histogram
#define RGROUPS 16             // reduce: groups along partial axis
#define RPER  (NBLK / RGROUPS) // 64 partials per group
#define WBLK  ((HSZ + 255) / 256)  // 38 word-blocks of 256 threads

// Kernel A: per-pixel softmax -> errs output + per-block LDS histogram.
// hist[c][k] packs cnt in low 16 bits, pos in high 16 bits (per-block pixel
// count == MPIX/NBLK == 1152 < 65536, no overflow).
// LDS 38,912 B * 4 blocks/CU = 155,648 B <= 160 KiB -> full 32-wave occupancy.
__global__ void __launch_bounds__(TPB) softmax_err_hist(
    const float* __restrict__ logits,
    const int* __restrict__ label,
    float* __restrict__ errs,              // [C, M]
    unsigned int* __restrict__ partial)    // [NBLK][HSZ]
{
    __shared__ unsigned int hist[HSZ];
    const int tid = threadIdx.x;
    const int b = blockIdx.x;

    for (int i = tid; i < HSZ; i += TPB) hist[i] = 0u;
    __syncthreads();

    for (int m = b * TPB + tid; m < MPIX; m += NBLK * TPB) {
        int n = m / HW;
        int base = m + n * (NCLS - 1) * HW;     // == n*C*HW + (m - n*HW)

        float v[NCLS];
        float mx = -1e30f;
#pragma unroll
        for (int c = 0; c < NCLS; ++c) {
            float x = logits[base + c * HW];
            v[c] = x;
            mx = fmaxf(mx, x);
        }
        float s = 0.f;
#pragma unroll
        for (int c = 0; c < NCLS; ++c) {
            float e = __expf(v[c] - mx);
            v[c] = e;
            s += e;
        }
        float inv = 1.0f / s;
        int lbl = label[m];
#pragma unroll
        for (int c = 0; c < NCLS; ++c) {
            float p = v[c] * inv;
            float err = (c == lbl) ? (1.0f - p) : p;
            errs[c * MPIX + m] = err;
            int k = (int)(err * (float)NB);
            k = min(k, NB - 1);
            k = max(k, 0);
            unsigned int add = 1u + ((c == lbl) ? 65536u : 0u);
            atomicAdd(&hist[c * NB + k], add);
        }
    }
    __syncthreads();

    // non-atomic coalesced flush to this block's private slice
    unsigned int* dst = partial + (size_t)b * HSZ;
    for (int i = tid; i < TPB * ((HSZ + TPB - 1) / TPB); i += TPB)
        if (i < HSZ) dst[i] = hist[i];
}

// Kernel R: reduce NBLK packed partials -> unpacked u32 cnt32/pos32.
// grid = WBLK * RGROUPS blocks of 256; thread owns one (c,k) word per group.
__global__ void __launch_bounds__(256) reduce_hist(
    const unsigned int* __restrict__ partial,   // [NBLK][HSZ]
    unsigned int* __restrict__ cnt32,           // [HSZ]
    unsigned int* __restrict__ pos32)           // [HSZ]
{
    int g = blockIdx.x / WBLK;
    int wb = blockIdx.x % WBLK;
    int i = wb * 256 + threadIdx.x;
    if (i >= HSZ) return;

    unsigned int sc = 0, sp = 0;
    const unsigned int* src = partial + (size_t)(g * RPER) * HSZ + i;
#pragma unroll 4
    for (int b = 0; b < RPER; ++b) {
        unsigned int w = src[(size_t)b * HSZ];
        sc += w & 0xFFFFu;
        sp += w >> 16;
    }
    atomicAdd(&cnt32[i], sc);
    atomicAdd(&pos32[i], sp);
}

__device__ __forceinline__ double jaccval(unsigned int n, unsigned int p, unsigned int npos)
{
    // J = 1 - (npos - p) / (npos + n - p); define 0/0 -> 0
    unsigned int denom = (npos - p) + n;
    if (denom == 0u) return 0.0;
    return 1.0 - (double)(npos - p) / (double)denom;
}

// Kernel B: one block per class. Suffix-scan + trapezoid integrate.
__global__ void __launch_bounds__(256) lovasz_scan(
    const unsigned int* __restrict__ cnt32,
    const unsigned int* __restrict__ pos32,
    float* __restrict__ out0)
{
    const int c = blockIdx.x;
    const int t = threadIdx.x;

    __shared__ unsigned int cntS[NB], posS[NB];
    cntS[t]       = cnt32[c * NB + t];
    cntS[t + 256] = cnt32[c * NB + t + 256];
    posS[t]       = pos32[c * NB + t];
    posS[t + 256] = pos32[c * NB + t + 256];
    __syncthreads();

    // per-thread chunk (2 buckets: 2t, 2t+1) sums
    unsigned int sc = cntS[2 * t] + cntS[2 * t + 1];
    unsigned int sp = posS[2 * t] + posS[2 * t + 1];

    __shared__ unsigned int scS[256], spS[256];
    scS[t] = sc; spS[t] = sp;
    __syncthreads();

    // suffix-exclusive counts (buckets above my chunk) + total positives
    unsigned int N = 0, P = 0, totP = 0;
    for (int u = 0; u < 256; ++u) {
        totP += spS[u];
        if (u > t) { N += scS[u]; P += spS[u]; }
    }

    // walk my 2 buckets from the top, trapezoid integrate
    double acc = 0.0;
    double Jprev = jaccval(N, P, totP);
    for (int k = 2 * t + 1; k >= 2 * t; --k) {
        N += cntS[k]; P += posS[k];
        double Jnew = jaccval(N, P, totP);
        acc += 0.5 * (Jprev + Jnew);
        Jprev = Jnew;
    }

    __shared__ double red[256];
    red[t] = acc;
    __syncthreads();
    for (int s2 = 128; s2 > 0; s2 >>= 1) {
        if (t < s2) red[t] += red[t + s2];
        __syncthreads();
    }
    if (t == 0) {
        double loss_c = red[0] / (double)NB;   // × bucket width
        atomicAdd(out0, (float)(loss_c / (double)NCLS));
    }
}

extern "C" void kernel_launch(void* const* d_in, const int* in_sizes, int n_in,
                              void* d_out, int out_size, void* d_ws, size_t ws_size,
                              hipStream_t stream)
{
    const float* logits = (const float*)d_in[0];
    const int*   label  = (const int*)d_in[1];
    float* out = (float*)d_out;

    // ws layout: [cnt32 HSZ][pos32 HSZ][partial NBLK*HSZ]
    unsigned int* cnt32   = (unsigned int*)d_ws;
    unsigned int* pos32   = cnt32 + HSZ;
    unsigned int* partial = pos32 + HSZ;

    hipMemsetAsync(d_ws, 0, (size_t)2 * HSZ * sizeof(unsigned int), stream);
    hipMemsetAsync(d_out, 0, sizeof(float), stream);

    softmax_err_hist<<<NBLK, TPB, 0, stream>>>(logits, label, out + 1, partial);
    reduce_hist<<<WBLK * RGROUPS, 256, 0, stream>>>(partial, cnt32, pos32);
    lovasz_scan<<<NCLS, 256, 0, stream>>>(cnt32, pos32, out);
}

// Round 5
// 194.887 us; speedup vs baseline: 1.0519x; 1.0519x over previous
//
#include <hip/hip_runtime.h>

// Problem constants (N,C,H,W) = (8,19,384,384)
#define NCLS 19
#define HW   147456            // 384*384
#define MPIX 1179648           // 8*384*384
#define NB   256               // histogram buckets per class (LDS-resident)
#define TPB  192               // 3 waves/block
#define NBLK 1536              // 6 blocks/CU exactly; 1536*192*4 == MPIX
#define HSZ  (NCLS * NB)       // 4864 packed u32 words per block histogram
#define RGROUPS 32             // reduce: groups along partial axis
#define RPER  (NBLK / RGROUPS) // 48 partials per group
#define WBLK  (HSZ / 256)      // 19 word-blocks of 256 threads (exact)

// Kernel A: 4 consecutive pixels per thread, float4 I/O.
// hist[c][k] packs cnt in low 16, pos in high 16 (block covers 768 px < 65536).
// LDS 19,456 B * 6 blocks/CU = 114 KiB <= 160 KiB.
__global__ void __launch_bounds__(TPB) softmax_err_hist(
    const float* __restrict__ logits,
    const int* __restrict__ label,
    float* __restrict__ errs,              // [C, M]
    unsigned int* __restrict__ partial)    // [NBLK][HSZ]
{
    __shared__ unsigned int hist[HSZ];
    const int tid = threadIdx.x;
    const int b = blockIdx.x;

    for (int i = tid; i < HSZ; i += TPB) hist[i] = 0u;
    __syncthreads();

    const int m = (b * TPB + tid) * 4;       // 4 consecutive pixels, same image
    const int n = m / HW;                     // HW % 4 == 0 -> all 4 px same n
    const int base = m + n * (NCLS - 1) * HW; // float4-aligned (m % 4 == 0)

    float4 v[NCLS];
    float4 mx = make_float4(-1e30f, -1e30f, -1e30f, -1e30f);
#pragma unroll
    for (int c = 0; c < NCLS; ++c) {
        float4 x = *(const float4*)(logits + base + c * HW);
        v[c] = x;
        mx.x = fmaxf(mx.x, x.x); mx.y = fmaxf(mx.y, x.y);
        mx.z = fmaxf(mx.z, x.z); mx.w = fmaxf(mx.w, x.w);
    }
    float4 s = make_float4(0.f, 0.f, 0.f, 0.f);
#pragma unroll
    for (int c = 0; c < NCLS; ++c) {
        float4 e;
        e.x = __expf(v[c].x - mx.x); e.y = __expf(v[c].y - mx.y);
        e.z = __expf(v[c].z - mx.z); e.w = __expf(v[c].w - mx.w);
        v[c] = e;
        s.x += e.x; s.y += e.y; s.z += e.z; s.w += e.w;
    }
    float4 inv = make_float4(1.f / s.x, 1.f / s.y, 1.f / s.z, 1.f / s.w);
    const int4 lbl = *(const int4*)(label + m);

#pragma unroll
    for (int c = 0; c < NCLS; ++c) {
        float4 p;
        p.x = v[c].x * inv.x; p.y = v[c].y * inv.y;
        p.z = v[c].z * inv.z; p.w = v[c].w * inv.w;
        float4 err;
        err.x = (c == lbl.x) ? (1.0f - p.x) : p.x;
        err.y = (c == lbl.y) ? (1.0f - p.y) : p.y;
        err.z = (c == lbl.z) ? (1.0f - p.z) : p.z;
        err.w = (c == lbl.w) ? (1.0f - p.w) : p.w;
        *(float4*)(errs + (size_t)c * MPIX + m) = err;

        int k0 = min(max((int)(err.x * (float)NB), 0), NB - 1);
        int k1 = min(max((int)(err.y * (float)NB), 0), NB - 1);
        int k2 = min(max((int)(err.z * (float)NB), 0), NB - 1);
        int k3 = min(max((int)(err.w * (float)NB), 0), NB - 1);
        atomicAdd(&hist[c * NB + k0], 1u + ((c == lbl.x) ? 65536u : 0u));
        atomicAdd(&hist[c * NB + k1], 1u + ((c == lbl.y) ? 65536u : 0u));
        atomicAdd(&hist[c * NB + k2], 1u + ((c == lbl.z) ? 65536u : 0u));
        atomicAdd(&hist[c * NB + k3], 1u + ((c == lbl.w) ? 65536u : 0u));
    }
    __syncthreads();

    // non-atomic coalesced flush to this block's private slice
    unsigned int* dst = partial + (size_t)b * HSZ;
    for (int i = tid; i < HSZ; i += TPB) dst[i] = hist[i];
}

// Kernel R: reduce NBLK packed partials -> unpacked u32 cnt32/pos32.
// grid = WBLK * RGROUPS blocks of 256; thread owns one (c,k) word per group.
__global__ void __launch_bounds__(256) reduce_hist(
    const unsigned int* __restrict__ partial,   // [NBLK][HSZ]
    unsigned int* __restrict__ cnt32,           // [HSZ]
    unsigned int* __restrict__ pos32)           // [HSZ]
{
    int g = blockIdx.x / WBLK;
    int wb = blockIdx.x % WBLK;
    int i = wb * 256 + threadIdx.x;             // < HSZ always (19*256 == HSZ)

    unsigned int sc = 0, sp = 0;
    const unsigned int* src = partial + (size_t)(g * RPER) * HSZ + i;
#pragma unroll 4
    for (int b = 0; b < RPER; ++b) {
        unsigned int w = src[(size_t)b * HSZ];
        sc += w & 0xFFFFu;
        sp += w >> 16;
    }
    atomicAdd(&cnt32[i], sc);
    atomicAdd(&pos32[i], sp);
}

__device__ __forceinline__ double jaccval(unsigned int n, unsigned int p, unsigned int npos)
{
    // J = 1 - (npos - p) / (npos + n - p); define 0/0 -> 0
    unsigned int denom = (npos - p) + n;
    if (denom == 0u) return 0.0;
    return 1.0 - (double)(npos - p) / (double)denom;
}

// Kernel B: one block per class; thread t owns bucket t. Suffix + trapezoid.
__global__ void __launch_bounds__(NB) lovasz_scan(
    const unsigned int* __restrict__ cnt32,
    const unsigned int* __restrict__ pos32,
    float* __restrict__ out0)
{
    const int c = blockIdx.x;
    const int t = threadIdx.x;

    __shared__ unsigned int cntS[NB], posS[NB];
    cntS[t] = cnt32[c * NB + t];
    posS[t] = pos32[c * NB + t];
    __syncthreads();

    // suffix-exclusive counts (buckets above t) + total positives
    unsigned int N = 0, P = 0, totP = 0;
    for (int u = 0; u < NB; ++u) {
        totP += posS[u];
        if (u > t) { N += cntS[u]; P += posS[u]; }
    }

    double Jprev = jaccval(N, P, totP);
    N += cntS[t]; P += posS[t];
    double Jnew = jaccval(N, P, totP);
    double acc = 0.5 * (Jprev + Jnew);

    __shared__ double red[NB];
    red[t] = acc;
    __syncthreads();
    for (int s2 = NB / 2; s2 > 0; s2 >>= 1) {
        if (t < s2) red[t] += red[t + s2];
        __syncthreads();
    }
    if (t == 0) {
        double loss_c = red[0] / (double)NB;   // × bucket width
        atomicAdd(out0, (float)(loss_c / (double)NCLS));
    }
}

extern "C" void kernel_launch(void* const* d_in, const int* in_sizes, int n_in,
                              void* d_out, int out_size, void* d_ws, size_t ws_size,
                              hipStream_t stream)
{
    const float* logits = (const float*)d_in[0];
    const int*   label  = (const int*)d_in[1];
    float* out = (float*)d_out;

    // ws layout: [cnt32 HSZ][pos32 HSZ][partial NBLK*HSZ]
    unsigned int* cnt32   = (unsigned int*)d_ws;
    unsigned int* pos32   = cnt32 + HSZ;
    unsigned int* partial = pos32 + HSZ;

    hipMemsetAsync(d_ws, 0, (size_t)2 * HSZ * sizeof(unsigned int), stream);
    hipMemsetAsync(d_out, 0, sizeof(float), stream);

    softmax_err_hist<<<NBLK, TPB, 0, stream>>>(logits, label, out + 1, partial);
    reduce_hist<<<WBLK * RGROUPS, 256, 0, stream>>>(partial, cnt32, pos32);
    lovasz_scan<<<NCLS, NB, 0, stream>>>(cnt32, pos32, out);
}